// Round 5
// baseline (529.486 us; speedup 1.0000x reference)
//
#include <hip/hip_runtime.h>
#include <hip/hip_bf16.h>

// SGNHeadLSS — round 11: chunked prefetch pipeline, bounded live ranges.
// r10 post-mortem: whole-tile register prefetch (32 floats live across
// all compute) spilled to scratch (FETCH 66->440MB, WRITE 26->217MB,
// 242us). Prefetch idea retained, live range fixed: next tile's x3d is
// loaded in four 8-float chunks; chunk i issues before a GEMM phase and
// is packed into a DOUBLE-BUFFERED sX right after it (peak +16 floats).
// sX dbuf costs +17.4KB LDS -> 49.9KB total, still 3 blocks/CU.
// Compute core identical to r9 (passed, absmax 0.024). NT stores
// dropped (r10 confounder). 2 barriers/tile.

#define NVOX 262144
#define NU   65536
#define NM   196608
#define CIN  128
#define CHALF 64
#define NCLS 20
#define TR   64
#define TILES 4
#define NBLK (NVOX / (TR * TILES))  // 1024

#define SXS 136   // sX row stride in u16 (272B, 16B-aligned)
#define SHS 72    // sH row stride in u16 (144B, 16B-aligned)
#define SOS 21    // sOut row stride in f32 (bank-conflict-free readback)
#define SXHALF (TR * SXS)  // one sX buffer in u16

// ws layout (u16 units), fragment order: [nt][kc][lane]*8
#define W1F  0       // nt4 kc4  -> 8192
#define W2F  8192    // nt8 kc2  -> 8192
#define SDBF 16384   // nt4 kc4  -> 8192
#define SSCF 24576   // nt2 kc2  -> 2048
#define AUXF 26624   // nt2 kc4  -> 4096
#define WS_WT 30720  // 61440 bytes of weights; rank[NVOX] int32 follows

typedef unsigned short u16;
typedef short    bf16x8 __attribute__((ext_vector_type(8)));
typedef float    f32x4  __attribute__((ext_vector_type(4)));

__device__ __forceinline__ u16 f2b(float f) {
    __hip_bfloat16 h = __float2bfloat16(f);
    return *(u16*)&h;
}

// B-frag layout: lane=q*16+n15 holds B[k=kc*32+q*8+j][n=nt*16+n15], j=0..7
__global__ void prep_weights(const float* __restrict__ w1,  const float* __restrict__ w2,
                             const float* __restrict__ sdbw,const float* __restrict__ sscw,
                             const float* __restrict__ auxw,
                             const int* __restrict__ uidx,  const int* __restrict__ midx,
                             u16* __restrict__ ws) {
    int i = blockIdx.x * blockDim.x + threadIdx.x;
    const int stride = gridDim.x * blockDim.x;
    int* __restrict__ rank = (int*)(ws + WS_WT);
    for (int t = i; t < NU; t += stride) rank[uidx[t]] = t;
    for (int t = i; t < NM; t += stride) rank[midx[t]] = -1;
    for (; i < WS_WT; i += stride) {
        float v;
        if (i < W2F) {                      // w1^frag: N=64, K=128
            int t = i, j = t & 7, lane = (t >> 3) & 63, kc = (t >> 9) & 3, nt = t >> 11;
            int k = kc*32 + (lane >> 4)*8 + j, n = nt*16 + (lane & 15);
            v = w1[k*CHALF + n];
        } else if (i < SDBF) {              // w2^frag: N=128, K=64
            int t = i - W2F, j = t & 7, lane = (t >> 3) & 63, kc = (t >> 9) & 1, nt = t >> 10;
            int k = kc*32 + (lane >> 4)*8 + j, n = nt*16 + (lane & 15);
            v = w2[k*CIN + n];
        } else if (i < SSCF) {              // sdb^frag: N=64, K=128
            int t = i - SDBF, j = t & 7, lane = (t >> 3) & 63, kc = (t >> 9) & 3, nt = t >> 11;
            int k = kc*32 + (lane >> 4)*8 + j, n = nt*16 + (lane & 15);
            v = sdbw[k*CHALF + n];
        } else if (i < AUXF) {              // ssc^frag: N=32(pad), K=64
            int t = i - SSCF, j = t & 7, lane = (t >> 3) & 63, kc = (t >> 9) & 1, nt = t >> 10;
            int k = kc*32 + (lane >> 4)*8 + j, n = nt*16 + (lane & 15);
            v = (n < NCLS) ? sscw[k*NCLS + n] : 0.f;
        } else {                            // aux^frag: N=32(pad), K=128
            int t = i - AUXF, j = t & 7, lane = (t >> 3) & 63, kc = (t >> 9) & 3, nt = t >> 11;
            int k = kc*32 + (lane >> 4)*8 + j, n = nt*16 + (lane & 15);
            v = (n < NCLS) ? auxw[k*NCLS + n] : 0.f;
        }
        ws[i] = f2b(v);
    }
}

__global__ __launch_bounds__(256, 3)
void sgn_mfma(const float* __restrict__ x3d,
              const float* __restrict__ b1,   const float* __restrict__ lng,
              const float* __restrict__ lnb,  const float* __restrict__ bb2,
              const float* __restrict__ sdbb, const float* __restrict__ sscb,
              const float* __restrict__ auxb,
              const int* __restrict__ rank,   const u16* __restrict__ wt,
              float* __restrict__ out)
{
    __shared__ __align__(16) u16 sX[2 * SXHALF];    // double-buffered vox tile
    __shared__ __align__(16) u16 sH[TR * SHS];      // h / d        [r][k]
    __shared__ __align__(16) float sOut[TR * SOS];  // ssc logits   [r][ch]
    __shared__ int sRank[2 * TR];

    const int tid  = threadIdx.x;
    const int base = (int)blockIdx.x * (TR * TILES);

    const int g  = tid >> 4;        // 0..15 -> channel pair base
    const int v0 = (tid & 15) * 4;  // voxel quad within tile

    // ---- prologue: tile 0 full load + pack (transient regs, r9-style) ----
    {
        #pragma unroll
        for (int i = 0; i < 4; ++i) {
            const int c0 = i*32 + g*2;
            f32x4 va = *(const f32x4*)&x3d[(size_t)c0     * NVOX + base + v0];
            f32x4 vb = *(const f32x4*)&x3d[(size_t)(c0+1) * NVOX + base + v0];
            #pragma unroll
            for (int j = 0; j < 4; ++j) {
                unsigned pk = (unsigned)f2b(va[j]) | ((unsigned)f2b(vb[j]) << 16);
                *(unsigned*)&sX[(v0 + j)*SXS + c0] = pk;
            }
        }
        if (tid < TR) sRank[tid] = rank[base + tid];
    }
    __syncthreads();

    const int m0   = (tid >> 6) * 16;  // wave's 16-row slice
    const int lane = tid & 63;
    const int q    = lane >> 4;
    const int n15  = lane & 15;
    const int kq   = q * 8;

    #pragma unroll 1
    for (int t = 0; t < TILES; ++t) {
        const int p0  = base + t * TR;
        const int cur = t & 1;
        const int nxt = cur ^ 1;
        u16* __restrict__ sXc = sX + cur * SXHALF;
        u16* __restrict__ sXn = sX + nxt * SXHALF;
        const bool pf = (t + 1 < TILES);
        const int p1 = p0 + TR;

        f32x4 pva, pvb;   // one prefetch chunk (8 floats) live at a time
        int rkn = -1;

        // ---- issue chunk 0 loads + next rank (latency covered by GEMM1) ----
        if (pf) {
            const int c0 = 0*32 + g*2;
            pva = *(const f32x4*)&x3d[(size_t)c0     * NVOX + p1 + v0];
            pvb = *(const f32x4*)&x3d[(size_t)(c0+1) * NVOX + p1 + v0];
            if (tid < TR) rkn = rank[p1 + tid];
        }

        // ---- GEMM1: feats[64x128] @ w1 -> LN -> leaky -> sH ----
        {
            f32x4 acc[4];
            #pragma unroll
            for (int nt = 0; nt < 4; ++nt) {
                const float b = b1[nt*16 + n15];
                acc[nt] = (f32x4){b, b, b, b};
            }
            #pragma unroll
            for (int kc = 0; kc < 4; ++kc) {
                const bf16x8 a = *(const bf16x8*)&sXc[(m0 + n15) * SXS + kc*32 + kq];
                #pragma unroll
                for (int nt = 0; nt < 4; ++nt) {
                    const bf16x8 b = *(const bf16x8*)&wt[W1F + ((nt*4 + kc)*64 + lane)*8];
                    acc[nt] = __builtin_amdgcn_mfma_f32_16x16x32_bf16(a, b, acc[nt], 0, 0, 0);
                }
            }
            float gv[4], ev[4];
            #pragma unroll
            for (int nt = 0; nt < 4; ++nt) { gv[nt] = lng[nt*16 + n15]; ev[nt] = lnb[nt*16 + n15]; }
            #pragma unroll
            for (int reg = 0; reg < 4; ++reg) {
                float s1 = acc[0][reg] + acc[1][reg] + acc[2][reg] + acc[3][reg];
                float s2 = acc[0][reg]*acc[0][reg] + acc[1][reg]*acc[1][reg]
                         + acc[2][reg]*acc[2][reg] + acc[3][reg]*acc[3][reg];
                #pragma unroll
                for (int m = 1; m <= 8; m <<= 1) {
                    s1 += __shfl_xor(s1, m, 64);
                    s2 += __shfl_xor(s2, m, 64);
                }
                const float mu  = s1 * (1.f/64.f);
                const float var = s2 * (1.f/64.f) - mu*mu;
                const float rs  = rsqrtf(var + 1e-5f);
                #pragma unroll
                for (int nt = 0; nt < 4; ++nt) {
                    float h = (acc[nt][reg] - mu) * rs * gv[nt] + ev[nt];
                    h = h > 0.f ? h : 0.01f*h;
                    sH[(m0 + q*4 + reg) * SHS + nt*16 + n15] = f2b(h);
                }
            }
        }

        // ---- pack chunk 0 -> sXn; issue chunk 1 ----
        if (pf) {
            const int c0 = 0*32 + g*2;
            #pragma unroll
            for (int j = 0; j < 4; ++j) {
                unsigned pk = (unsigned)f2b(pva[j]) | ((unsigned)f2b(pvb[j]) << 16);
                *(unsigned*)&sXn[(v0 + j)*SXS + c0] = pk;
            }
            const int c1 = 1*32 + g*2;
            pva = *(const f32x4*)&x3d[(size_t)c1     * NVOX + p1 + v0];
            pvb = *(const f32x4*)&x3d[(size_t)(c1+1) * NVOX + p1 + v0];
        }

        // ---- GEMM2: h[64x64] @ w2 -> prior; overwrite MASKED rows of sXc ----
        {
            f32x4 acc2[8];
            #pragma unroll
            for (int nt = 0; nt < 8; ++nt) {
                const float b = bb2[nt*16 + n15];
                acc2[nt] = (f32x4){b, b, b, b};
            }
            #pragma unroll
            for (int kc = 0; kc < 2; ++kc) {
                const bf16x8 a = *(const bf16x8*)&sH[(m0 + n15) * SHS + kc*32 + kq];
                #pragma unroll
                for (int nt = 0; nt < 8; ++nt) {
                    const bf16x8 b = *(const bf16x8*)&wt[W2F + ((nt*2 + kc)*64 + lane)*8];
                    acc2[nt] = __builtin_amdgcn_mfma_f32_16x16x32_bf16(a, b, acc2[nt], 0, 0, 0);
                }
            }
            #pragma unroll
            for (int reg = 0; reg < 4; ++reg) {
                const int row = m0 + q*4 + reg;
                if (sRank[cur*TR + row] < 0) {   // masked -> vox = prior
                    #pragma unroll
                    for (int nt = 0; nt < 8; ++nt)
                        sXc[row * SXS + nt*16 + n15] = f2b(acc2[nt][reg]);
                }                                // unmasked -> vox = feats
            }
        }

        // ---- pack chunk 1 -> sXn; issue chunk 2 ----
        if (pf) {
            const int c1 = 1*32 + g*2;
            #pragma unroll
            for (int j = 0; j < 4; ++j) {
                unsigned pk = (unsigned)f2b(pva[j]) | ((unsigned)f2b(pvb[j]) << 16);
                *(unsigned*)&sXn[(v0 + j)*SXS + c1] = pk;
            }
            const int c2 = 2*32 + g*2;
            pva = *(const f32x4*)&x3d[(size_t)c2     * NVOX + p1 + v0];
            pvb = *(const f32x4*)&x3d[(size_t)(c2+1) * NVOX + p1 + v0];
        }

        // ---- SDB: vox[64x128] @ sdb_w -> leaky -> sH (= d) ----
        {
            f32x4 accd[4];
            #pragma unroll
            for (int nt = 0; nt < 4; ++nt) {
                const float b = sdbb[nt*16 + n15];
                accd[nt] = (f32x4){b, b, b, b};
            }
            #pragma unroll
            for (int kc = 0; kc < 4; ++kc) {
                const bf16x8 a = *(const bf16x8*)&sXc[(m0 + n15) * SXS + kc*32 + kq];
                #pragma unroll
                for (int nt = 0; nt < 4; ++nt) {
                    const bf16x8 b = *(const bf16x8*)&wt[SDBF + ((nt*4 + kc)*64 + lane)*8];
                    accd[nt] = __builtin_amdgcn_mfma_f32_16x16x32_bf16(a, b, accd[nt], 0, 0, 0);
                }
            }
            #pragma unroll
            for (int reg = 0; reg < 4; ++reg)
                #pragma unroll
                for (int nt = 0; nt < 4; ++nt) {
                    float vv = accd[nt][reg];
                    vv = vv > 0.f ? vv : 0.01f*vv;
                    sH[(m0 + q*4 + reg) * SHS + nt*16 + n15] = f2b(vv);
                }
        }

        // ---- pack chunk 2 -> sXn; issue chunk 3 ----
        if (pf) {
            const int c2 = 2*32 + g*2;
            #pragma unroll
            for (int j = 0; j < 4; ++j) {
                unsigned pk = (unsigned)f2b(pva[j]) | ((unsigned)f2b(pvb[j]) << 16);
                *(unsigned*)&sXn[(v0 + j)*SXS + c2] = pk;
            }
            const int c3 = 3*32 + g*2;
            pva = *(const f32x4*)&x3d[(size_t)c3     * NVOX + p1 + v0];
            pvb = *(const f32x4*)&x3d[(size_t)(c3+1) * NVOX + p1 + v0];
        }

        // ---- SSC: d[64x64] @ ssc_w[64x20] -> sOut (LDS, [row][ch]) ----
        {
            f32x4 accs[2];
            #pragma unroll
            for (int nt = 0; nt < 2; ++nt) {
                const int col = nt*16 + n15;
                const float b = (col < NCLS) ? sscb[col] : 0.f;
                accs[nt] = (f32x4){b, b, b, b};
            }
            #pragma unroll
            for (int kc = 0; kc < 2; ++kc) {
                const bf16x8 a = *(const bf16x8*)&sH[(m0 + n15) * SHS + kc*32 + kq];
                #pragma unroll
                for (int nt = 0; nt < 2; ++nt) {
                    const bf16x8 b = *(const bf16x8*)&wt[SSCF + ((nt*2 + kc)*64 + lane)*8];
                    accs[nt] = __builtin_amdgcn_mfma_f32_16x16x32_bf16(a, b, accs[nt], 0, 0, 0);
                }
            }
            #pragma unroll
            for (int reg = 0; reg < 4; ++reg) {
                const int row = m0 + q*4 + reg;
                sOut[row*SOS + n15] = accs[0][reg];
                if (n15 < 4) sOut[row*SOS + 16 + n15] = accs[1][reg];
            }
        }

        // ---- AUX: feats @ aux_w (all rows; only unmasked stored) ----
        f32x4 acca[2];
        {
            #pragma unroll
            for (int nt = 0; nt < 2; ++nt) {
                const int col = nt*16 + n15;
                const float b = (col < NCLS) ? auxb[col] : 0.f;
                acca[nt] = (f32x4){b, b, b, b};
            }
            #pragma unroll
            for (int kc = 0; kc < 4; ++kc) {
                const bf16x8 a = *(const bf16x8*)&sXc[(m0 + n15) * SXS + kc*32 + kq];
                #pragma unroll
                for (int nt = 0; nt < 2; ++nt) {
                    const bf16x8 b = *(const bf16x8*)&wt[AUXF + ((nt*4 + kc)*64 + lane)*8];
                    acca[nt] = __builtin_amdgcn_mfma_f32_16x16x32_bf16(a, b, acca[nt], 0, 0, 0);
                }
            }
        }

        // ---- pack chunk 3 -> sXn; publish next sRank ----
        if (pf) {
            const int c3 = 3*32 + g*2;
            #pragma unroll
            for (int j = 0; j < 4; ++j) {
                unsigned pk = (unsigned)f2b(pva[j]) | ((unsigned)f2b(pvb[j]) << 16);
                *(unsigned*)&sXn[(v0 + j)*SXS + c3] = pk;
            }
            if (tid < TR) sRank[nxt*TR + tid] = rkn;
        }

        // current-tile ranks -> regs (for aux store after barrier)
        int rk4[4];
        #pragma unroll
        for (int reg = 0; reg < 4; ++reg) rk4[reg] = sRank[cur*TR + m0 + q*4 + reg];

        __syncthreads();   // barrier A: sOut + sXn complete, sXc reads done

        // ---- coalesced SSC store: out[ch][p0+vox] <- sOut[vox][ch] ----
        #pragma unroll
        for (int jj = 0; jj < 5; ++jj) {
            const int i = tid + jj*256;       // i = ch*64 + vox
            out[(size_t)(i >> 6) * NVOX + p0 + (i & 63)] = sOut[(i & 63) * SOS + (i >> 6)];
        }

        // ---- AUX store, predicated on unmasked (rank row) ----
        {
            const size_t abase = (size_t)NCLS * NVOX;
            #pragma unroll
            for (int reg = 0; reg < 4; ++reg) {
                const int rk = rk4[reg];
                if (rk >= 0) {
                    out[abase + (size_t)rk * NCLS + n15] = acca[0][reg];
                    if (n15 < 4)
                        out[abase + (size_t)rk * NCLS + 16 + n15] = acca[1][reg];
                }
            }
        }

        __syncthreads();   // barrier B: sOut free for next tile's SSC
    }
}

extern "C" void kernel_launch(void* const* d_in, const int* in_sizes, int n_in,
                              void* d_out, int out_size, void* d_ws, size_t ws_size,
                              hipStream_t stream) {
    const float* x3d  = (const float*)d_in[0];
    const float* w1   = (const float*)d_in[1];
    const float* b1   = (const float*)d_in[2];
    const float* lng  = (const float*)d_in[3];
    const float* lnb  = (const float*)d_in[4];
    const float* w2   = (const float*)d_in[5];
    const float* bb2  = (const float*)d_in[6];
    const float* sdbw = (const float*)d_in[7];
    const float* sdbb = (const float*)d_in[8];
    const float* sscw = (const float*)d_in[9];
    const float* sscb = (const float*)d_in[10];
    const float* auxw = (const float*)d_in[11];
    const float* auxb = (const float*)d_in[12];
    const int*   uidx = (const int*)d_in[13];
    const int*   midx = (const int*)d_in[14];
    float* out = (float*)d_out;
    u16*   wt  = (u16*)d_ws;
    const int* rank = (const int*)((const char*)d_ws + WS_WT*2);

    hipLaunchKernelGGL(prep_weights, dim3(128), dim3(256), 0, stream,
                       w1, w2, sdbw, sscw, auxw, uidx, midx, wt);
    hipLaunchKernelGGL(sgn_mfma, dim3(NBLK), dim3(256), 0, stream,
                       x3d, b1, lng, lnb, bb2, sdbb, sscb, auxb,
                       rank, wt, out);
}

// Round 6
// 261.923 us; speedup vs baseline: 2.0215x; 2.0215x over previous
//
#include <hip/hip_runtime.h>
#include <hip/hip_bf16.h>

// SGNHeadLSS — round 12: 32 rows per wave (2 independent MFMA chains).
// r10/r11 post-mortem: ANY cross-phase register prefetch of x3d spills
// to scratch (FETCH/WRITE explode 5-10x) — abandoned. Reverting to the
// clean r9 structure (2 barriers, direct global b-frags, phase-local
// live ranges) and attacking the real constraint: per-wave latency
// chain. Each wave now owns 32 rows (TR=128/block, grid 2048): every
// b-frag load feeds 2 MFMAs (per-row VMEM halved) and each phase has
// 2 independent dep chains. Compute math identical to r9 (passed,
// absmax 0.024). LDS 64.5KB -> 2 blocks/CU; (256,2) -> no VGPR cap
// pressure, no spill.

#define NVOX 262144
#define NU   65536
#define NM   196608
#define CIN  128
#define CHALF 64
#define NCLS 20
#define TR   128
#define NBLK (NVOX / TR)  // 2048

#define SXS 136   // sX row stride in u16 (272B, 16B-aligned)
#define SHS 72    // sH row stride in u16 (144B, 16B-aligned)
#define SOS 21    // sOut row stride in f32 (bank-conflict-free readback)

// ws layout (u16 units), fragment order: [nt][kc][lane]*8
#define W1F  0       // nt4 kc4  -> 8192
#define W2F  8192    // nt8 kc2  -> 8192
#define SDBF 16384   // nt4 kc4  -> 8192
#define SSCF 24576   // nt2 kc2  -> 2048
#define AUXF 26624   // nt2 kc4  -> 4096
#define WS_WT 30720  // 61440 bytes of weights; rank[NVOX] int32 follows

typedef unsigned short u16;
typedef short    bf16x8 __attribute__((ext_vector_type(8)));
typedef float    f32x4  __attribute__((ext_vector_type(4)));

__device__ __forceinline__ u16 f2b(float f) {
    __hip_bfloat16 h = __float2bfloat16(f);
    return *(u16*)&h;
}

// B-frag layout: lane=q*16+n15 holds B[k=kc*32+q*8+j][n=nt*16+n15], j=0..7
__global__ void prep_weights(const float* __restrict__ w1,  const float* __restrict__ w2,
                             const float* __restrict__ sdbw,const float* __restrict__ sscw,
                             const float* __restrict__ auxw,
                             const int* __restrict__ uidx,  const int* __restrict__ midx,
                             u16* __restrict__ ws) {
    int i = blockIdx.x * blockDim.x + threadIdx.x;
    const int stride = gridDim.x * blockDim.x;
    int* __restrict__ rank = (int*)(ws + WS_WT);
    for (int t = i; t < NU; t += stride) rank[uidx[t]] = t;
    for (int t = i; t < NM; t += stride) rank[midx[t]] = -1;
    for (; i < WS_WT; i += stride) {
        float v;
        if (i < W2F) {                      // w1^frag: N=64, K=128
            int t = i, j = t & 7, lane = (t >> 3) & 63, kc = (t >> 9) & 3, nt = t >> 11;
            int k = kc*32 + (lane >> 4)*8 + j, n = nt*16 + (lane & 15);
            v = w1[k*CHALF + n];
        } else if (i < SDBF) {              // w2^frag: N=128, K=64
            int t = i - W2F, j = t & 7, lane = (t >> 3) & 63, kc = (t >> 9) & 1, nt = t >> 10;
            int k = kc*32 + (lane >> 4)*8 + j, n = nt*16 + (lane & 15);
            v = w2[k*CIN + n];
        } else if (i < SSCF) {              // sdb^frag: N=64, K=128
            int t = i - SDBF, j = t & 7, lane = (t >> 3) & 63, kc = (t >> 9) & 3, nt = t >> 11;
            int k = kc*32 + (lane >> 4)*8 + j, n = nt*16 + (lane & 15);
            v = sdbw[k*CHALF + n];
        } else if (i < AUXF) {              // ssc^frag: N=32(pad), K=64
            int t = i - SSCF, j = t & 7, lane = (t >> 3) & 63, kc = (t >> 9) & 1, nt = t >> 10;
            int k = kc*32 + (lane >> 4)*8 + j, n = nt*16 + (lane & 15);
            v = (n < NCLS) ? sscw[k*NCLS + n] : 0.f;
        } else {                            // aux^frag: N=32(pad), K=128
            int t = i - AUXF, j = t & 7, lane = (t >> 3) & 63, kc = (t >> 9) & 3, nt = t >> 11;
            int k = kc*32 + (lane >> 4)*8 + j, n = nt*16 + (lane & 15);
            v = (n < NCLS) ? auxw[k*NCLS + n] : 0.f;
        }
        ws[i] = f2b(v);
    }
}

__global__ __launch_bounds__(256, 2)
void sgn_mfma(const float* __restrict__ x3d,
              const float* __restrict__ b1,   const float* __restrict__ lng,
              const float* __restrict__ lnb,  const float* __restrict__ bb2,
              const float* __restrict__ sdbb, const float* __restrict__ sscb,
              const float* __restrict__ auxb,
              const int* __restrict__ rank,   const u16* __restrict__ wt,
              float* __restrict__ out)
{
    __shared__ __align__(16) u16 sX[TR * SXS];      // feats / vox  [r][k]  34.8KB
    __shared__ __align__(16) u16 sH[TR * SHS];      // h / d        [r][k]  18.4KB
    __shared__ __align__(16) float sOut[TR * SOS];  // ssc logits   [r][ch] 10.8KB
    __shared__ int sRank[TR];

    const int tid = threadIdx.x;
    const int p0  = (int)blockIdx.x * TR;

    // ---- dense coalesced x3d load + pack (transient regs, phase-local) ----
    // thread covers channels {c0,c0+1} for c0 = g*2 + 16i, voxels v0..v0+3
    const int g  = tid >> 5;        // 0..7
    const int v0 = (tid & 31) * 4;  // 0..124
    #pragma unroll
    for (int i = 0; i < 8; ++i) {
        const int c0 = g*2 + 16*i;
        f32x4 va = *(const f32x4*)&x3d[(size_t)c0     * NVOX + p0 + v0];
        f32x4 vb = *(const f32x4*)&x3d[(size_t)(c0+1) * NVOX + p0 + v0];
        #pragma unroll
        for (int j = 0; j < 4; ++j) {
            unsigned pk = (unsigned)f2b(va[j]) | ((unsigned)f2b(vb[j]) << 16);
            *(unsigned*)&sX[(v0 + j)*SXS + c0] = pk;
        }
    }
    if (tid < TR) sRank[tid] = rank[p0 + tid];
    __syncthreads();   // barrier 1: sX + sRank cross-wave

    const int W0   = (tid >> 6) * 32;  // wave's 32-row slice
    const int lane = tid & 63;
    const int q    = lane >> 4;
    const int n15  = lane & 15;
    const int kq   = q * 8;

    // ---- GEMM1: feats[128x128] @ w1 -> LN -> leaky -> sH ----
    {
        f32x4 acc[2][4];
        #pragma unroll
        for (int nt = 0; nt < 4; ++nt) {
            const float b = b1[nt*16 + n15];
            acc[0][nt] = (f32x4){b, b, b, b};
            acc[1][nt] = (f32x4){b, b, b, b};
        }
        #pragma unroll
        for (int kc = 0; kc < 4; ++kc) {
            const bf16x8 a0 = *(const bf16x8*)&sX[(W0      + n15) * SXS + kc*32 + kq];
            const bf16x8 a1 = *(const bf16x8*)&sX[(W0 + 16 + n15) * SXS + kc*32 + kq];
            #pragma unroll
            for (int nt = 0; nt < 4; ++nt) {
                const bf16x8 b = *(const bf16x8*)&wt[W1F + ((nt*4 + kc)*64 + lane)*8];
                acc[0][nt] = __builtin_amdgcn_mfma_f32_16x16x32_bf16(a0, b, acc[0][nt], 0, 0, 0);
                acc[1][nt] = __builtin_amdgcn_mfma_f32_16x16x32_bf16(a1, b, acc[1][nt], 0, 0, 0);
            }
        }
        float gv[4], ev[4];
        #pragma unroll
        for (int nt = 0; nt < 4; ++nt) { gv[nt] = lng[nt*16 + n15]; ev[nt] = lnb[nt*16 + n15]; }
        #pragma unroll
        for (int mm = 0; mm < 2; ++mm)
            #pragma unroll
            for (int reg = 0; reg < 4; ++reg) {
                float s1 = acc[mm][0][reg] + acc[mm][1][reg] + acc[mm][2][reg] + acc[mm][3][reg];
                float s2 = acc[mm][0][reg]*acc[mm][0][reg] + acc[mm][1][reg]*acc[mm][1][reg]
                         + acc[mm][2][reg]*acc[mm][2][reg] + acc[mm][3][reg]*acc[mm][3][reg];
                #pragma unroll
                for (int m = 1; m <= 8; m <<= 1) {
                    s1 += __shfl_xor(s1, m, 64);
                    s2 += __shfl_xor(s2, m, 64);
                }
                const float mu  = s1 * (1.f/64.f);
                const float var = s2 * (1.f/64.f) - mu*mu;
                const float rs  = rsqrtf(var + 1e-5f);
                #pragma unroll
                for (int nt = 0; nt < 4; ++nt) {
                    float h = (acc[mm][nt][reg] - mu) * rs * gv[nt] + ev[nt];
                    h = h > 0.f ? h : 0.01f*h;
                    sH[(W0 + mm*16 + q*4 + reg) * SHS + nt*16 + n15] = f2b(h);
                }
            }
    }

    // ---- GEMM2: h[128x64] @ w2 -> prior; overwrite MASKED rows of sX ----
    {
        f32x4 acc2[2][8];
        #pragma unroll
        for (int nt = 0; nt < 8; ++nt) {
            const float b = bb2[nt*16 + n15];
            acc2[0][nt] = (f32x4){b, b, b, b};
            acc2[1][nt] = (f32x4){b, b, b, b};
        }
        #pragma unroll
        for (int kc = 0; kc < 2; ++kc) {
            const bf16x8 a0 = *(const bf16x8*)&sH[(W0      + n15) * SHS + kc*32 + kq];
            const bf16x8 a1 = *(const bf16x8*)&sH[(W0 + 16 + n15) * SHS + kc*32 + kq];
            #pragma unroll
            for (int nt = 0; nt < 8; ++nt) {
                const bf16x8 b = *(const bf16x8*)&wt[W2F + ((nt*2 + kc)*64 + lane)*8];
                acc2[0][nt] = __builtin_amdgcn_mfma_f32_16x16x32_bf16(a0, b, acc2[0][nt], 0, 0, 0);
                acc2[1][nt] = __builtin_amdgcn_mfma_f32_16x16x32_bf16(a1, b, acc2[1][nt], 0, 0, 0);
            }
        }
        #pragma unroll
        for (int mm = 0; mm < 2; ++mm)
            #pragma unroll
            for (int reg = 0; reg < 4; ++reg) {
                const int row = W0 + mm*16 + q*4 + reg;
                if (sRank[row] < 0) {          // masked -> vox = prior
                    #pragma unroll
                    for (int nt = 0; nt < 8; ++nt)
                        sX[row * SXS + nt*16 + n15] = f2b(acc2[mm][nt][reg]);
                }                              // unmasked -> vox = feats
            }
    }

    // ---- SDB: vox[128x128] @ sdb_w -> leaky -> sH (= d) ----
    {
        f32x4 accd[2][4];
        #pragma unroll
        for (int nt = 0; nt < 4; ++nt) {
            const float b = sdbb[nt*16 + n15];
            accd[0][nt] = (f32x4){b, b, b, b};
            accd[1][nt] = (f32x4){b, b, b, b};
        }
        #pragma unroll
        for (int kc = 0; kc < 4; ++kc) {
            const bf16x8 a0 = *(const bf16x8*)&sX[(W0      + n15) * SXS + kc*32 + kq];
            const bf16x8 a1 = *(const bf16x8*)&sX[(W0 + 16 + n15) * SXS + kc*32 + kq];
            #pragma unroll
            for (int nt = 0; nt < 4; ++nt) {
                const bf16x8 b = *(const bf16x8*)&wt[SDBF + ((nt*4 + kc)*64 + lane)*8];
                accd[0][nt] = __builtin_amdgcn_mfma_f32_16x16x32_bf16(a0, b, accd[0][nt], 0, 0, 0);
                accd[1][nt] = __builtin_amdgcn_mfma_f32_16x16x32_bf16(a1, b, accd[1][nt], 0, 0, 0);
            }
        }
        #pragma unroll
        for (int mm = 0; mm < 2; ++mm)
            #pragma unroll
            for (int reg = 0; reg < 4; ++reg)
                #pragma unroll
                for (int nt = 0; nt < 4; ++nt) {
                    float vv = accd[mm][nt][reg];
                    vv = vv > 0.f ? vv : 0.01f*vv;
                    sH[(W0 + mm*16 + q*4 + reg) * SHS + nt*16 + n15] = f2b(vv);
                }
    }

    // ---- SSC: d[128x64] @ ssc_w[64x20] -> sOut (LDS, [row][ch]) ----
    {
        f32x4 accs[2][2];
        #pragma unroll
        for (int nt = 0; nt < 2; ++nt) {
            const int col = nt*16 + n15;
            const float b = (col < NCLS) ? sscb[col] : 0.f;
            accs[0][nt] = (f32x4){b, b, b, b};
            accs[1][nt] = (f32x4){b, b, b, b};
        }
        #pragma unroll
        for (int kc = 0; kc < 2; ++kc) {
            const bf16x8 a0 = *(const bf16x8*)&sH[(W0      + n15) * SHS + kc*32 + kq];
            const bf16x8 a1 = *(const bf16x8*)&sH[(W0 + 16 + n15) * SHS + kc*32 + kq];
            #pragma unroll
            for (int nt = 0; nt < 2; ++nt) {
                const bf16x8 b = *(const bf16x8*)&wt[SSCF + ((nt*2 + kc)*64 + lane)*8];
                accs[0][nt] = __builtin_amdgcn_mfma_f32_16x16x32_bf16(a0, b, accs[0][nt], 0, 0, 0);
                accs[1][nt] = __builtin_amdgcn_mfma_f32_16x16x32_bf16(a1, b, accs[1][nt], 0, 0, 0);
            }
        }
        #pragma unroll
        for (int mm = 0; mm < 2; ++mm)
            #pragma unroll
            for (int reg = 0; reg < 4; ++reg) {
                const int row = W0 + mm*16 + q*4 + reg;
                sOut[row*SOS + n15] = accs[mm][0][reg];
                if (n15 < 4) sOut[row*SOS + 16 + n15] = accs[mm][1][reg];
            }
    }

    // ---- AUX: feats @ aux_w; store predicated on unmasked (pre-barrier) ----
    {
        f32x4 acca[2][2];
        #pragma unroll
        for (int nt = 0; nt < 2; ++nt) {
            const int col = nt*16 + n15;
            const float b = (col < NCLS) ? auxb[col] : 0.f;
            acca[0][nt] = (f32x4){b, b, b, b};
            acca[1][nt] = (f32x4){b, b, b, b};
        }
        #pragma unroll
        for (int kc = 0; kc < 4; ++kc) {
            const bf16x8 a0 = *(const bf16x8*)&sX[(W0      + n15) * SXS + kc*32 + kq];
            const bf16x8 a1 = *(const bf16x8*)&sX[(W0 + 16 + n15) * SXS + kc*32 + kq];
            #pragma unroll
            for (int nt = 0; nt < 2; ++nt) {
                const bf16x8 b = *(const bf16x8*)&wt[AUXF + ((nt*4 + kc)*64 + lane)*8];
                acca[0][nt] = __builtin_amdgcn_mfma_f32_16x16x32_bf16(a0, b, acca[0][nt], 0, 0, 0);
                acca[1][nt] = __builtin_amdgcn_mfma_f32_16x16x32_bf16(a1, b, acca[1][nt], 0, 0, 0);
            }
        }
        const size_t abase = (size_t)NCLS * NVOX;
        #pragma unroll
        for (int mm = 0; mm < 2; ++mm)
            #pragma unroll
            for (int reg = 0; reg < 4; ++reg) {
                const int rk = sRank[W0 + mm*16 + q*4 + reg];
                if (rk >= 0) {
                    out[abase + (size_t)rk * NCLS + n15] = acca[mm][0][reg];
                    if (n15 < 4)
                        out[abase + (size_t)rk * NCLS + 16 + n15] = acca[mm][1][reg];
                }
            }
    }
    __syncthreads();   // barrier 2: sOut complete (cross-wave readback)

    // ---- coalesced SSC store: out[ch][p0+vox] <- sOut[vox][ch] ----
    #pragma unroll
    for (int jj = 0; jj < 10; ++jj) {
        const int i = tid + jj*256;       // 2560 floats: i = ch*128 + vox
        out[(size_t)(i >> 7) * NVOX + p0 + (i & 127)] = sOut[(i & 127) * SOS + (i >> 7)];
    }
}

extern "C" void kernel_launch(void* const* d_in, const int* in_sizes, int n_in,
                              void* d_out, int out_size, void* d_ws, size_t ws_size,
                              hipStream_t stream) {
    const float* x3d  = (const float*)d_in[0];
    const float* w1   = (const float*)d_in[1];
    const float* b1   = (const float*)d_in[2];
    const float* lng  = (const float*)d_in[3];
    const float* lnb  = (const float*)d_in[4];
    const float* w2   = (const float*)d_in[5];
    const float* bb2  = (const float*)d_in[6];
    const float* sdbw = (const float*)d_in[7];
    const float* sdbb = (const float*)d_in[8];
    const float* sscw = (const float*)d_in[9];
    const float* sscb = (const float*)d_in[10];
    const float* auxw = (const float*)d_in[11];
    const float* auxb = (const float*)d_in[12];
    const int*   uidx = (const int*)d_in[13];
    const int*   midx = (const int*)d_in[14];
    float* out = (float*)d_out;
    u16*   wt  = (u16*)d_ws;
    const int* rank = (const int*)((const char*)d_ws + WS_WT*2);

    hipLaunchKernelGGL(prep_weights, dim3(128), dim3(256), 0, stream,
                       w1, w2, sdbw, sscw, auxw, uidx, midx, wt);
    hipLaunchKernelGGL(sgn_mfma, dim3(NBLK), dim3(256), 0, stream,
                       x3d, b1, lng, lnb, bb2, sdbb, sscb, auxb,
                       rank, wt, out);
}